// Round 3
// baseline (1490.014 us; speedup 1.0000x reference)
//
#include <hip/hip_runtime.h>
#include <math.h>

#define HID 128
#define NHEAD 4
#define CH 32
#define NLAYER 3
#define EDIM 3
#define EPSLN 1e-5f
#define SLOPE 0.2f

typedef __attribute__((address_space(1))) const void gvoid;
typedef __attribute__((address_space(3))) void lvoid;

// ---------------------------------------------------------------- CSR build
__global__ void k_count(const int* __restrict__ dst, int* __restrict__ deg, int E) {
    int i = blockIdx.x * blockDim.x + threadIdx.x;
    if (i < E) atomicAdd(&deg[dst[i]], 1);
}

__global__ __launch_bounds__(1024) void k_scan(const int* __restrict__ deg,
                                               int* __restrict__ rowstart,
                                               int* __restrict__ cursor, int n) {
    __shared__ int sw[16];
    __shared__ int scarry;
    int tid = threadIdx.x, lane = tid & 63, wid = tid >> 6;
    if (tid == 0) scarry = 0;
    __syncthreads();
    for (int base = 0; base < n; base += 1024) {
        int i = base + tid;
        int v = (i < n) ? deg[i] : 0;
        int x = v;
#pragma unroll
        for (int o = 1; o < 64; o <<= 1) { int y = __shfl_up(x, o, 64); if (lane >= o) x += y; }
        if (lane == 63) sw[wid] = x;
        __syncthreads();
        int carry = scarry;
        if (tid < 16) {
            int s = sw[tid];
#pragma unroll
            for (int o = 1; o < 16; o <<= 1) { int y = __shfl_up(s, o, 64); if (tid >= o) s += y; }
            sw[tid] = s;
        }
        __syncthreads();
        int wofs = (wid == 0) ? 0 : sw[wid - 1];
        int incl = carry + wofs + x;
        if (i < n) { rowstart[i] = incl - v; cursor[i] = incl - v; }
        __syncthreads();
        if (tid == 0) scarry = carry + sw[15];
        __syncthreads();
    }
    if (tid == 0) rowstart[n] = scarry;
}

__global__ void k_fill(const int* __restrict__ src, const int* __restrict__ dst,
                       const float* __restrict__ eattr, int* __restrict__ cursor,
                       int* __restrict__ srcs, float4* __restrict__ ea4, int E) {
    int i = blockIdx.x * blockDim.x + threadIdx.x;
    if (i < E) {
        int slot = atomicAdd(&cursor[dst[i]], 1);
        srcs[slot] = src[i];
        ea4[slot] = make_float4(eattr[3 * i], eattr[3 * i + 1], eattr[3 * i + 2], 0.f);
    }
}

// ---------------------------------------------------------------- GEMM  Y = X @ W (+bias)
__device__ __forceinline__ void fma4(float4& a, const float4 h, const float4 w0,
                                     const float4 w1, const float4 w2, const float4 w3) {
    a.x = fmaf(h.x, w0.x, a.x); a.x = fmaf(h.y, w1.x, a.x); a.x = fmaf(h.z, w2.x, a.x); a.x = fmaf(h.w, w3.x, a.x);
    a.y = fmaf(h.x, w0.y, a.y); a.y = fmaf(h.y, w1.y, a.y); a.y = fmaf(h.z, w2.y, a.y); a.y = fmaf(h.w, w3.y, a.y);
    a.z = fmaf(h.x, w0.z, a.z); a.z = fmaf(h.y, w1.z, a.z); a.z = fmaf(h.z, w2.z, a.z); a.z = fmaf(h.w, w3.z, a.z);
    a.w = fmaf(h.x, w0.w, a.w); a.w = fmaf(h.y, w1.w, a.w); a.w = fmaf(h.z, w2.w, a.w); a.w = fmaf(h.w, w3.w, a.w);
}

__global__ __launch_bounds__(256) void k_gemm128(const float* __restrict__ X,
                                                 const float* __restrict__ W0,
                                                 const float* __restrict__ W1,
                                                 float* __restrict__ Y0,
                                                 float* __restrict__ Y1,
                                                 const float* __restrict__ bias, int N) {
    __shared__ float sW[HID * HID];  // 64 KB
    const float* W = (blockIdx.y == 0) ? W0 : W1;
    float* Y = (blockIdx.y == 0) ? Y0 : Y1;
    int tid = threadIdx.x;
    const float4* W4 = (const float4*)W;
    float4* sW4 = (float4*)sW;
#pragma unroll
    for (int i = 0; i < 16; i++) sW4[tid + i * 256] = W4[tid + i * 256];
    __syncthreads();

    int cg = tid & 31, ng = tid >> 5;
    int col = cg * 4;
    float4 bv = make_float4(0.f, 0.f, 0.f, 0.f);
    if (bias) bv = *(const float4*)&bias[col];

    for (int nb = blockIdx.x * 32; nb < N; nb += gridDim.x * 32) {
        int n0 = nb + ng * 4;
        if (n0 >= N) continue;
        const float* x0 = X + (size_t)n0 * HID;
        float4 a0 = bv, a1 = bv, a2 = bv, a3 = bv;
#pragma unroll 2
        for (int k = 0; k < HID; k += 4) {
            float4 h0 = *(const float4*)&x0[k];
            float4 h1 = *(const float4*)&x0[HID + k];
            float4 h2 = *(const float4*)&x0[2 * HID + k];
            float4 h3 = *(const float4*)&x0[3 * HID + k];
            float4 w0 = *(const float4*)&sW[(k + 0) * HID + col];
            float4 w1 = *(const float4*)&sW[(k + 1) * HID + col];
            float4 w2 = *(const float4*)&sW[(k + 2) * HID + col];
            float4 w3 = *(const float4*)&sW[(k + 3) * HID + col];
            fma4(a0, h0, w0, w1, w2, w3);
            fma4(a1, h1, w0, w1, w2, w3);
            fma4(a2, h2, w0, w1, w2, w3);
            fma4(a3, h3, w0, w1, w2, w3);
        }
        float* y0 = Y + (size_t)n0 * HID + col;
        *(float4*)&y0[0] = a0;
        *(float4*)&y0[HID] = a1;
        *(float4*)&y0[2 * HID] = a2;
        *(float4*)&y0[3 * HID] = a3;
    }
}

// ---------------------------------------------------------------- GATv2 aggregate
// One wave per destination node. Per chunk of 16 edges:
//   - coalesced metadata load (lane e holds srcs/ea of edge base+e, clamped)
//   - 8x global_load_lds(width=16): each call gathers TWO edges' 512B xl rows
//     into a wave-private LDS slab (no dest VGPR -> compiler cannot serialize;
//     all gathers stay in flight together)
//   - s_waitcnt, then compute from LDS; broadcasts use literal-index __shfl
//     (lowers to v_readlane, SALU - no DS latency on the critical path)
// No __syncthreads anywhere (waves have different trip counts); LDS slab is
// wave-private so wave-level s_waitcnt suffices.
__global__ __launch_bounds__(256) void k_aggregate(const float* __restrict__ xl,
                                                   const float* __restrict__ xr,
                                                   const int* __restrict__ srcs,
                                                   const float4* __restrict__ ea4,
                                                   const int* __restrict__ rowstart,
                                                   const float* __restrict__ We,
                                                   const float* __restrict__ att,
                                                   float* __restrict__ outp,
                                                   float* __restrict__ red, int N) {
    __shared__ float sxl[4][16 * HID];  // 4 waves x 8KB
    int wid = threadIdx.x >> 6;
    int lane = threadIdx.x & 63;
    int node = blockIdx.x * 4 + wid;
    if (node >= N) return;
    int c0 = lane * 2;
    int head = lane >> 4;
    int half = lane >> 5;    // 0: lanes 0-31, 1: lanes 32-63
    int qlane = lane & 31;

    float we00 = We[c0], we01 = We[c0 + 1];
    float we10 = We[HID + c0], we11 = We[HID + c0 + 1];
    float we20 = We[2 * HID + c0], we21 = We[2 * HID + c0 + 1];
    float at0 = att[head * CH + (c0 & 31)];
    float at1 = att[head * CH + (c0 & 31) + 1];
    float2 xrv = *(const float2*)&xr[(size_t)node * HID + c0];

    int beg = rowstart[node], end = rowstart[node + 1];
    float l = 0.f, acc0 = 0.f, acc1 = 0.f;
    float* myl = &sxl[wid][0];

    for (int base = beg; base < end; base += 16) {
        int cnt = end - base;
        if (cnt > 16) cnt = 16;
        int idx = base + ((lane < cnt) ? lane : (cnt - 1));
        int s_l = srcs[idx];
        float4 ea_l = ea4[idx];
        // issue all gathers; two edges per call (1KB/wave-call)
#pragma unroll
        for (int t = 0; t < 8; t++) {
            if (2 * t < cnt) {
                int sa = __shfl(s_l, 2 * t);       // literal index -> v_readlane
                int sb = __shfl(s_l, 2 * t + 1);   // clamped dup if 2t+1>=cnt
                int s2 = half ? sb : sa;
                const float* gp = xl + (size_t)s2 * HID + qlane * 4;
                __builtin_amdgcn_global_load_lds((gvoid*)gp,
                                                 (lvoid*)(myl + 2 * t * HID), 16, 0, 0);
            }
        }
        __builtin_amdgcn_s_waitcnt(0);  // drain gathers before LDS reads
#pragma unroll
        for (int t = 0; t < 16; t++) {
            if (t < cnt) {  // wave-uniform guard
                float2 xv = *(const float2*)&myl[t * HID + c0];
                float eax = __shfl(ea_l.x, t);
                float eay = __shfl(ea_l.y, t);
                float eaz = __shfl(ea_l.z, t);
                float m0 = xv.x + xrv.x + fmaf(eax, we00, fmaf(eay, we10, eaz * we20));
                float m1 = xv.y + xrv.y + fmaf(eax, we01, fmaf(eay, we11, eaz * we21));
                m0 = (m0 > 0.f) ? m0 : SLOPE * m0;
                m1 = (m1 > 0.f) ? m1 : SLOPE * m1;
                float part = fmaf(m0, at0, m1 * at1);
                part += __shfl_xor(part, 1);
                part += __shfl_xor(part, 2);
                part += __shfl_xor(part, 4);
                part += __shfl_xor(part, 8);
                float p = __expf(part);  // softmax shift dropped: logits O(10), fp32-safe
                l += p;
                acc0 = fmaf(p, xv.x, acc0);
                acc1 = fmaf(p, xv.y, acc1);
            }
        }
    }
    float inv = 1.f / (l + 1e-16f);
    float o0 = acc0 * inv, o1 = acc1 * inv;
    *(float2*)&outp[(size_t)node * HID + c0] = make_float2(o0, o1);

    // fused graph-LN partial reduction (sum, sumsq) across the wave
    float ssum = o0 + o1;
    float ssq = fmaf(o0, o0, o1 * o1);
#pragma unroll
    for (int o = 32; o >= 1; o >>= 1) { ssum += __shfl_xor(ssum, o); ssq += __shfl_xor(ssq, o); }
    if (lane == 0) {
        int slot = (blockIdx.x & 63) * 2;
        atomicAdd(&red[slot], ssum);
        atomicAdd(&red[slot + 1], ssq);
    }
}

// ---------------------------------------------------------------- LN finish + apply
__global__ void k_finish(const float* __restrict__ red, float* __restrict__ scal, float M) {
    int t = threadIdx.x;  // 64 threads
    float s = red[t * 2], q = red[t * 2 + 1];
#pragma unroll
    for (int o = 32; o >= 1; o >>= 1) { s += __shfl_xor(s, o); q += __shfl_xor(q, o); }
    if (t == 0) {
        float mean = s / M;
        float var = q / M - mean * mean;
        scal[0] = mean;
        scal[1] = rsqrtf(var + EPSLN);
    }
}

__global__ __launch_bounds__(256) void k_ln_gelu(const float4* __restrict__ in4,
                                                 const float* __restrict__ w,
                                                 const float* __restrict__ b,
                                                 const float* __restrict__ scal,
                                                 float4* __restrict__ out4, int n4) {
    int i = blockIdx.x * blockDim.x + threadIdx.x;
    if (i >= n4) return;
    float mean = scal[0], inv = scal[1];
    float4 v = in4[i];
    int col = (i * 4) & 127;
    float4 wv = *(const float4*)&w[col];
    float4 bv = *(const float4*)&b[col];
    float r[4] = {v.x, v.y, v.z, v.w};
    float wr[4] = {wv.x, wv.y, wv.z, wv.w};
    float br[4] = {bv.x, bv.y, bv.z, bv.w};
#pragma unroll
    for (int j = 0; j < 4; j++) {
        float t = fmaf((r[j] - mean) * inv, wr[j], br[j]);
        r[j] = 0.5f * t * (1.f + erff(t * 0.70710678118654752f));
    }
    out4[i] = make_float4(r[0], r[1], r[2], r[3]);
}

// ---------------------------------------------------------------- launch
extern "C" void kernel_launch(void* const* d_in, const int* in_sizes, int n_in,
                              void* d_out, int out_size, void* d_ws, size_t ws_size,
                              hipStream_t stream) {
    const float* x = (const float*)d_in[0];
    const int* ei = (const int*)d_in[1];
    const float* eattr = (const float*)d_in[2];
    const float* Wl = (const float*)d_in[3];
    const float* Wr = (const float*)d_in[4];
    const float* We = (const float*)d_in[5];
    const float* att = (const float*)d_in[6];
    const float* lnw = (const float*)d_in[7];
    const float* lnb = (const float*)d_in[8];
    const float* Wout = (const float*)d_in[9];
    const float* bout = (const float*)d_in[10];
    float* out = (float*)d_out;

    int N = in_sizes[0] / HID;
    int E = in_sizes[1] / 2;
    const int* src = ei;
    const int* dst = ei + E;

    char* w = (char*)d_ws;
    float* h_buf = (float*)w;   w += (size_t)N * HID * 4;
    float* tmp = (float*)w;     w += (size_t)N * HID * 4;
    float* xl = (float*)w;      w += (size_t)N * HID * 4;
    float* xr = (float*)w;      w += (size_t)N * HID * 4;
    float4* ea4 = (float4*)w;   w += (size_t)E * 16;
    float* red = (float*)w;     w += 128 * 4;
    float* scal = (float*)w;    w += 16;
    int* deg = (int*)w;         w += (size_t)N * 4;
    int* cursor = (int*)w;      w += (size_t)N * 4;
    int* rowstart = (int*)w;    w += (size_t)(N + 1) * 4;
    int* srcs = (int*)w;        w += (size_t)E * 4;

    // CSR build (graph identical across layers -> build once per call)
    hipMemsetAsync(deg, 0, (size_t)N * 4, stream);
    k_count<<<(E + 255) / 256, 256, 0, stream>>>(dst, deg, E);
    k_scan<<<1, 1024, 0, stream>>>(deg, rowstart, cursor, N);
    k_fill<<<(E + 255) / 256, 256, 0, stream>>>(src, dst, eattr, cursor, srcs, ea4, E);

    const float* hin = x;
    for (int l = 0; l < NLAYER; l++) {
        k_gemm128<<<dim3(640, 2), 256, 0, stream>>>(
            hin, Wl + (size_t)l * HID * HID, Wr + (size_t)l * HID * HID, xl, xr, nullptr, N);
        hipMemsetAsync(red, 0, 128 * 4, stream);
        k_aggregate<<<(N + 3) / 4, 256, 0, stream>>>(
            xl, xr, srcs, ea4, rowstart,
            We + (size_t)l * EDIM * HID, att + (size_t)l * NHEAD * CH, tmp, red, N);
        k_finish<<<1, 64, 0, stream>>>(red, scal, (float)N * (float)HID);
        k_ln_gelu<<<((N * HID / 4) + 255) / 256, 256, 0, stream>>>(
            (const float4*)tmp, lnw + (size_t)l * HID, lnb + (size_t)l * HID, scal,
            (float4*)h_buf, N * HID / 4);
        hin = h_buf;
    }
    k_gemm128<<<dim3(640, 1), 256, 0, stream>>>(hin, Wout, Wout, out, out, bout, N);
}

// Round 4
// 1434.558 us; speedup vs baseline: 1.0387x; 1.0387x over previous
//
#include <hip/hip_runtime.h>
#include <math.h>

#define HID 128
#define NHEAD 4
#define CH 32
#define NLAYER 3
#define EDIM 3
#define EPSLN 1e-5f
#define SLOPE 0.2f

// ---------------------------------------------------------------- CSR build
__global__ void k_count(const int* __restrict__ dst, int* __restrict__ deg, int E) {
    int i = blockIdx.x * blockDim.x + threadIdx.x;
    if (i < E) atomicAdd(&deg[dst[i]], 1);
}

__global__ __launch_bounds__(1024) void k_scan(const int* __restrict__ deg,
                                               int* __restrict__ rowstart,
                                               int* __restrict__ cursor, int n) {
    __shared__ int sw[16];
    __shared__ int scarry;
    int tid = threadIdx.x, lane = tid & 63, wid = tid >> 6;
    if (tid == 0) scarry = 0;
    __syncthreads();
    for (int base = 0; base < n; base += 1024) {
        int i = base + tid;
        int v = (i < n) ? deg[i] : 0;
        int x = v;
#pragma unroll
        for (int o = 1; o < 64; o <<= 1) { int y = __shfl_up(x, o, 64); if (lane >= o) x += y; }
        if (lane == 63) sw[wid] = x;
        __syncthreads();
        int carry = scarry;
        if (tid < 16) {
            int s = sw[tid];
#pragma unroll
            for (int o = 1; o < 16; o <<= 1) { int y = __shfl_up(s, o, 64); if (tid >= o) s += y; }
            sw[tid] = s;
        }
        __syncthreads();
        int wofs = (wid == 0) ? 0 : sw[wid - 1];
        int incl = carry + wofs + x;
        if (i < n) { rowstart[i] = incl - v; cursor[i] = incl - v; }
        __syncthreads();
        if (tid == 0) scarry = carry + sw[15];
        __syncthreads();
    }
    if (tid == 0) rowstart[n] = scarry;
}

__global__ void k_fill(const int* __restrict__ src, const int* __restrict__ dst,
                       const float* __restrict__ eattr, int* __restrict__ cursor,
                       int* __restrict__ srcs, float4* __restrict__ ea4, int E) {
    int i = blockIdx.x * blockDim.x + threadIdx.x;
    if (i < E) {
        int slot = atomicAdd(&cursor[dst[i]], 1);
        srcs[slot] = src[i];
        ea4[slot] = make_float4(eattr[3 * i], eattr[3 * i + 1], eattr[3 * i + 2], 0.f);
    }
}

// ---------------------------------------------------------------- GEMM  Y = X @ W (+bias)
__device__ __forceinline__ void fma4(float4& a, const float4 h, const float4 w0,
                                     const float4 w1, const float4 w2, const float4 w3) {
    a.x = fmaf(h.x, w0.x, a.x); a.x = fmaf(h.y, w1.x, a.x); a.x = fmaf(h.z, w2.x, a.x); a.x = fmaf(h.w, w3.x, a.x);
    a.y = fmaf(h.x, w0.y, a.y); a.y = fmaf(h.y, w1.y, a.y); a.y = fmaf(h.z, w2.y, a.y); a.y = fmaf(h.w, w3.y, a.y);
    a.z = fmaf(h.x, w0.z, a.z); a.z = fmaf(h.y, w1.z, a.z); a.z = fmaf(h.z, w2.z, a.z); a.z = fmaf(h.w, w3.z, a.z);
    a.w = fmaf(h.x, w0.w, a.w); a.w = fmaf(h.y, w1.w, a.w); a.w = fmaf(h.z, w2.w, a.w); a.w = fmaf(h.w, w3.w, a.w);
}

__global__ __launch_bounds__(256) void k_gemm128(const float* __restrict__ X,
                                                 const float* __restrict__ W0,
                                                 const float* __restrict__ W1,
                                                 float* __restrict__ Y0,
                                                 float* __restrict__ Y1,
                                                 const float* __restrict__ bias, int N) {
    __shared__ float sW[HID * HID];  // 64 KB
    const float* W = (blockIdx.y == 0) ? W0 : W1;
    float* Y = (blockIdx.y == 0) ? Y0 : Y1;
    int tid = threadIdx.x;
    const float4* W4 = (const float4*)W;
    float4* sW4 = (float4*)sW;
#pragma unroll
    for (int i = 0; i < 16; i++) sW4[tid + i * 256] = W4[tid + i * 256];
    __syncthreads();

    int cg = tid & 31, ng = tid >> 5;
    int col = cg * 4;
    float4 bv = make_float4(0.f, 0.f, 0.f, 0.f);
    if (bias) bv = *(const float4*)&bias[col];

    for (int nb = blockIdx.x * 32; nb < N; nb += gridDim.x * 32) {
        int n0 = nb + ng * 4;
        if (n0 >= N) continue;
        const float* x0 = X + (size_t)n0 * HID;
        float4 a0 = bv, a1 = bv, a2 = bv, a3 = bv;
#pragma unroll 2
        for (int k = 0; k < HID; k += 4) {
            float4 h0 = *(const float4*)&x0[k];
            float4 h1 = *(const float4*)&x0[HID + k];
            float4 h2 = *(const float4*)&x0[2 * HID + k];
            float4 h3 = *(const float4*)&x0[3 * HID + k];
            float4 w0 = *(const float4*)&sW[(k + 0) * HID + col];
            float4 w1 = *(const float4*)&sW[(k + 1) * HID + col];
            float4 w2 = *(const float4*)&sW[(k + 2) * HID + col];
            float4 w3 = *(const float4*)&sW[(k + 3) * HID + col];
            fma4(a0, h0, w0, w1, w2, w3);
            fma4(a1, h1, w0, w1, w2, w3);
            fma4(a2, h2, w0, w1, w2, w3);
            fma4(a3, h3, w0, w1, w2, w3);
        }
        float* y0 = Y + (size_t)n0 * HID + col;
        *(float4*)&y0[0] = a0;
        *(float4*)&y0[HID] = a1;
        *(float4*)&y0[2 * HID] = a2;
        *(float4*)&y0[3 * HID] = a3;
    }
}

// ---------------------------------------------------------------- GATv2 aggregate
// One wave per destination node. Per 8-edge chunk, three flat phases:
//   A: 8 WAVE-UNIFORM loads of srcs[beg+t]  (uniform address -> HW broadcast,
//      no shfl; beg/end readfirstlane'd so the compiler can SMEM-ize them)
//   B: 8 independent float2 gathers of xl rows (addr = s[t]*512 + lane*8);
//      the only non-uniform traffic, 8-deep in flight per wave
//   C: 8 uniform ea4 loads + compute (shfl only in the 16-lane logit reduce)
// No LDS, no explicit waitcnt -> high occupancy, deep MLP.
__global__ __launch_bounds__(256) void k_aggregate(const float* __restrict__ xl,
                                                   const float* __restrict__ xr,
                                                   const int* __restrict__ srcs,
                                                   const float4* __restrict__ ea4,
                                                   const int* __restrict__ rowstart,
                                                   const float* __restrict__ We,
                                                   const float* __restrict__ att,
                                                   float* __restrict__ outp,
                                                   float* __restrict__ red, int N) {
    int wid = threadIdx.x >> 6;
    int lane = threadIdx.x & 63;
    int node = blockIdx.x * 4 + wid;
    if (node >= N) return;
    int c0 = lane * 2;
    int head = lane >> 4;

    float we00 = We[c0], we01 = We[c0 + 1];
    float we10 = We[HID + c0], we11 = We[HID + c0 + 1];
    float we20 = We[2 * HID + c0], we21 = We[2 * HID + c0 + 1];
    float at0 = att[head * CH + (c0 & 31)];
    float at1 = att[head * CH + (c0 & 31) + 1];
    float2 xrv = *(const float2*)&xr[(size_t)node * HID + c0];

    int beg = __builtin_amdgcn_readfirstlane(rowstart[node]);
    int end = __builtin_amdgcn_readfirstlane(rowstart[node + 1]);
    float l = 0.f, acc0 = 0.f, acc1 = 0.f;

    for (int base = beg; base < end; base += 8) {
        int s[8];
#pragma unroll
        for (int t = 0; t < 8; t++) {
            int idx = base + t; idx = (idx < end) ? idx : (end - 1);
            s[t] = srcs[idx];                       // uniform address
        }
        float2 xv[8];
#pragma unroll
        for (int t = 0; t < 8; t++)
            xv[t] = *(const float2*)&xl[(size_t)s[t] * HID + c0];  // 8 gathers in flight
        float4 ev[8];
#pragma unroll
        for (int t = 0; t < 8; t++) {
            int idx = base + t; idx = (idx < end) ? idx : (end - 1);
            ev[t] = ea4[idx];                       // uniform address
        }
#pragma unroll
        for (int t = 0; t < 8; t++) {
            float m0 = xv[t].x + xrv.x + fmaf(ev[t].x, we00, fmaf(ev[t].y, we10, ev[t].z * we20));
            float m1 = xv[t].y + xrv.y + fmaf(ev[t].x, we01, fmaf(ev[t].y, we11, ev[t].z * we21));
            m0 = (m0 > 0.f) ? m0 : SLOPE * m0;
            m1 = (m1 > 0.f) ? m1 : SLOPE * m1;
            float part = fmaf(m0, at0, m1 * at1);
            part += __shfl_xor(part, 1);
            part += __shfl_xor(part, 2);
            part += __shfl_xor(part, 4);
            part += __shfl_xor(part, 8);
            // softmax shift dropped: logits O(10), fp32-safe; clamped dup edges get p=0
            float p = (base + t < end) ? __expf(part) : 0.f;
            l += p;
            acc0 = fmaf(p, xv[t].x, acc0);
            acc1 = fmaf(p, xv[t].y, acc1);
        }
    }
    float inv = 1.f / (l + 1e-16f);
    float o0 = acc0 * inv, o1 = acc1 * inv;
    *(float2*)&outp[(size_t)node * HID + c0] = make_float2(o0, o1);

    // fused graph-LN partial reduction (sum, sumsq) across the wave
    float ssum = o0 + o1;
    float ssq = fmaf(o0, o0, o1 * o1);
#pragma unroll
    for (int o = 32; o >= 1; o >>= 1) { ssum += __shfl_xor(ssum, o); ssq += __shfl_xor(ssq, o); }
    if (lane == 0) {
        int slot = (blockIdx.x & 63) * 2;
        atomicAdd(&red[slot], ssum);
        atomicAdd(&red[slot + 1], ssq);
    }
}

// ---------------------------------------------------------------- LN finish + apply
__global__ void k_finish(const float* __restrict__ red, float* __restrict__ scal, float M) {
    int t = threadIdx.x;  // 64 threads
    float s = red[t * 2], q = red[t * 2 + 1];
#pragma unroll
    for (int o = 32; o >= 1; o >>= 1) { s += __shfl_xor(s, o); q += __shfl_xor(q, o); }
    if (t == 0) {
        float mean = s / M;
        float var = q / M - mean * mean;
        scal[0] = mean;
        scal[1] = rsqrtf(var + EPSLN);
    }
}

__global__ __launch_bounds__(256) void k_ln_gelu(const float4* __restrict__ in4,
                                                 const float* __restrict__ w,
                                                 const float* __restrict__ b,
                                                 const float* __restrict__ scal,
                                                 float4* __restrict__ out4, int n4) {
    int i = blockIdx.x * blockDim.x + threadIdx.x;
    if (i >= n4) return;
    float mean = scal[0], inv = scal[1];
    float4 v = in4[i];
    int col = (i * 4) & 127;
    float4 wv = *(const float4*)&w[col];
    float4 bv = *(const float4*)&b[col];
    float r[4] = {v.x, v.y, v.z, v.w};
    float wr[4] = {wv.x, wv.y, wv.z, wv.w};
    float br[4] = {bv.x, bv.y, bv.z, bv.w};
#pragma unroll
    for (int j = 0; j < 4; j++) {
        float t = fmaf((r[j] - mean) * inv, wr[j], br[j]);
        r[j] = 0.5f * t * (1.f + erff(t * 0.70710678118654752f));
    }
    out4[i] = make_float4(r[0], r[1], r[2], r[3]);
}

// ---------------------------------------------------------------- launch
extern "C" void kernel_launch(void* const* d_in, const int* in_sizes, int n_in,
                              void* d_out, int out_size, void* d_ws, size_t ws_size,
                              hipStream_t stream) {
    const float* x = (const float*)d_in[0];
    const int* ei = (const int*)d_in[1];
    const float* eattr = (const float*)d_in[2];
    const float* Wl = (const float*)d_in[3];
    const float* Wr = (const float*)d_in[4];
    const float* We = (const float*)d_in[5];
    const float* att = (const float*)d_in[6];
    const float* lnw = (const float*)d_in[7];
    const float* lnb = (const float*)d_in[8];
    const float* Wout = (const float*)d_in[9];
    const float* bout = (const float*)d_in[10];
    float* out = (float*)d_out;

    int N = in_sizes[0] / HID;
    int E = in_sizes[1] / 2;
    const int* src = ei;
    const int* dst = ei + E;

    char* w = (char*)d_ws;
    float* h_buf = (float*)w;   w += (size_t)N * HID * 4;
    float* tmp = (float*)w;     w += (size_t)N * HID * 4;
    float* xl = (float*)w;      w += (size_t)N * HID * 4;
    float* xr = (float*)w;      w += (size_t)N * HID * 4;
    float4* ea4 = (float4*)w;   w += (size_t)E * 16;
    float* red = (float*)w;     w += 128 * 4;
    float* scal = (float*)w;    w += 16;
    int* deg = (int*)w;         w += (size_t)N * 4;
    int* cursor = (int*)w;      w += (size_t)N * 4;
    int* rowstart = (int*)w;    w += (size_t)(N + 1) * 4;
    int* srcs = (int*)w;        w += (size_t)E * 4;

    // CSR build (graph identical across layers -> build once per call)
    hipMemsetAsync(deg, 0, (size_t)N * 4, stream);
    k_count<<<(E + 255) / 256, 256, 0, stream>>>(dst, deg, E);
    k_scan<<<1, 1024, 0, stream>>>(deg, rowstart, cursor, N);
    k_fill<<<(E + 255) / 256, 256, 0, stream>>>(src, dst, eattr, cursor, srcs, ea4, E);

    const float* hin = x;
    for (int l = 0; l < NLAYER; l++) {
        k_gemm128<<<dim3(640, 2), 256, 0, stream>>>(
            hin, Wl + (size_t)l * HID * HID, Wr + (size_t)l * HID * HID, xl, xr, nullptr, N);
        hipMemsetAsync(red, 0, 128 * 4, stream);
        k_aggregate<<<(N + 3) / 4, 256, 0, stream>>>(
            xl, xr, srcs, ea4, rowstart,
            We + (size_t)l * EDIM * HID, att + (size_t)l * NHEAD * CH, tmp, red, N);
        k_finish<<<1, 64, 0, stream>>>(red, scal, (float)N * (float)HID);
        k_ln_gelu<<<((N * HID / 4) + 255) / 256, 256, 0, stream>>>(
            (const float4*)tmp, lnw + (size_t)l * HID, lnb + (size_t)l * HID, scal,
            (float4*)h_buf, N * HID / 4);
        hin = h_buf;
    }
    k_gemm128<<<dim3(640, 1), 256, 0, stream>>>(hin, Wout, Wout, out, out, bout, N);
}

// Round 5
// 795.378 us; speedup vs baseline: 1.8733x; 1.8036x over previous
//
#include <hip/hip_runtime.h>
#include <math.h>

#define HID 128
#define NHEAD 4
#define CH 32
#define NLAYER 3
#define EDIM 3
#define EPSLN 1e-5f
#define SLOPE 0.2f
#define RSLOTS 4096   // LN-reduction slots (pairs); 32 KB buffer

// ---------------------------------------------------------------- CSR build
__global__ void k_count(const int* __restrict__ dst, int* __restrict__ deg, int E) {
    int i = blockIdx.x * blockDim.x + threadIdx.x;
    if (i < E) atomicAdd(&deg[dst[i]], 1);
}

__global__ __launch_bounds__(1024) void k_scan(const int* __restrict__ deg,
                                               int* __restrict__ rowstart,
                                               int* __restrict__ cursor, int n) {
    __shared__ int sw[16];
    __shared__ int scarry;
    int tid = threadIdx.x, lane = tid & 63, wid = tid >> 6;
    if (tid == 0) scarry = 0;
    __syncthreads();
    for (int base = 0; base < n; base += 1024) {
        int i = base + tid;
        int v = (i < n) ? deg[i] : 0;
        int x = v;
#pragma unroll
        for (int o = 1; o < 64; o <<= 1) { int y = __shfl_up(x, o, 64); if (lane >= o) x += y; }
        if (lane == 63) sw[wid] = x;
        __syncthreads();
        int carry = scarry;
        if (tid < 16) {
            int s = sw[tid];
#pragma unroll
            for (int o = 1; o < 16; o <<= 1) { int y = __shfl_up(s, o, 64); if (tid >= o) s += y; }
            sw[tid] = s;
        }
        __syncthreads();
        int wofs = (wid == 0) ? 0 : sw[wid - 1];
        int incl = carry + wofs + x;
        if (i < n) { rowstart[i] = incl - v; cursor[i] = incl - v; }
        __syncthreads();
        if (tid == 0) scarry = carry + sw[15];
        __syncthreads();
    }
    if (tid == 0) rowstart[n] = scarry;
}

__global__ void k_fill(const int* __restrict__ src, const int* __restrict__ dst,
                       const float* __restrict__ eattr, int* __restrict__ cursor,
                       int* __restrict__ srcs, float4* __restrict__ ea4, int E) {
    int i = blockIdx.x * blockDim.x + threadIdx.x;
    if (i < E) {
        int slot = atomicAdd(&cursor[dst[i]], 1);
        srcs[slot] = src[i];
        ea4[slot] = make_float4(eattr[3 * i], eattr[3 * i + 1], eattr[3 * i + 2], 0.f);
    }
}

// ---------------------------------------------------------------- GEMM  Y = X @ W (+bias)
__device__ __forceinline__ void fma4(float4& a, const float4 h, const float4 w0,
                                     const float4 w1, const float4 w2, const float4 w3) {
    a.x = fmaf(h.x, w0.x, a.x); a.x = fmaf(h.y, w1.x, a.x); a.x = fmaf(h.z, w2.x, a.x); a.x = fmaf(h.w, w3.x, a.x);
    a.y = fmaf(h.x, w0.y, a.y); a.y = fmaf(h.y, w1.y, a.y); a.y = fmaf(h.z, w2.y, a.y); a.y = fmaf(h.w, w3.y, a.y);
    a.z = fmaf(h.x, w0.z, a.z); a.z = fmaf(h.y, w1.z, a.z); a.z = fmaf(h.z, w2.z, a.z); a.z = fmaf(h.w, w3.z, a.z);
    a.w = fmaf(h.x, w0.w, a.w); a.w = fmaf(h.y, w1.w, a.w); a.w = fmaf(h.z, w2.w, a.w); a.w = fmaf(h.w, w3.w, a.w);
}

__global__ __launch_bounds__(256) void k_gemm128(const float* __restrict__ X,
                                                 const float* __restrict__ W0,
                                                 const float* __restrict__ W1,
                                                 float* __restrict__ Y0,
                                                 float* __restrict__ Y1,
                                                 const float* __restrict__ bias, int N) {
    __shared__ float sW[HID * HID];  // 64 KB
    const float* W = (blockIdx.y == 0) ? W0 : W1;
    float* Y = (blockIdx.y == 0) ? Y0 : Y1;
    int tid = threadIdx.x;
    const float4* W4 = (const float4*)W;
    float4* sW4 = (float4*)sW;
#pragma unroll
    for (int i = 0; i < 16; i++) sW4[tid + i * 256] = W4[tid + i * 256];
    __syncthreads();

    int cg = tid & 31, ng = tid >> 5;
    int col = cg * 4;
    float4 bv = make_float4(0.f, 0.f, 0.f, 0.f);
    if (bias) bv = *(const float4*)&bias[col];

    for (int nb = blockIdx.x * 32; nb < N; nb += gridDim.x * 32) {
        int n0 = nb + ng * 4;
        if (n0 >= N) continue;
        const float* x0 = X + (size_t)n0 * HID;
        float4 a0 = bv, a1 = bv, a2 = bv, a3 = bv;
#pragma unroll 2
        for (int k = 0; k < HID; k += 4) {
            float4 h0 = *(const float4*)&x0[k];
            float4 h1 = *(const float4*)&x0[HID + k];
            float4 h2 = *(const float4*)&x0[2 * HID + k];
            float4 h3 = *(const float4*)&x0[3 * HID + k];
            float4 w0 = *(const float4*)&sW[(k + 0) * HID + col];
            float4 w1 = *(const float4*)&sW[(k + 1) * HID + col];
            float4 w2 = *(const float4*)&sW[(k + 2) * HID + col];
            float4 w3 = *(const float4*)&sW[(k + 3) * HID + col];
            fma4(a0, h0, w0, w1, w2, w3);
            fma4(a1, h1, w0, w1, w2, w3);
            fma4(a2, h2, w0, w1, w2, w3);
            fma4(a3, h3, w0, w1, w2, w3);
        }
        float* y0 = Y + (size_t)n0 * HID + col;
        *(float4*)&y0[0] = a0;
        *(float4*)&y0[HID] = a1;
        *(float4*)&y0[2 * HID] = a2;
        *(float4*)&y0[3 * HID] = a3;
    }
}

// ---------------------------------------------------------------- GATv2 aggregate
// FOUR nodes per wave, edge loops interleaved: 4 independent memory chains
// per wave (structural MLP the scheduler cannot collapse), 4x fewer waves.
// LN reduction: one atomic pair per wave into (wave_id & 4095) of a 32 KB
// slot array -> ~25 atomics per cacheline TOTAL (R1-R4 funneled 100K atomics
// onto 8 lines; that L2 RMW serialization was the invariant ~310 us wall).
__global__ __launch_bounds__(256) void k_aggregate(const float* __restrict__ xl,
                                                   const float* __restrict__ xr,
                                                   const int* __restrict__ srcs,
                                                   const float4* __restrict__ ea4,
                                                   const int* __restrict__ rowstart,
                                                   const float* __restrict__ We,
                                                   const float* __restrict__ att,
                                                   float* __restrict__ outp,
                                                   float* __restrict__ red, int N) {
    int wid = threadIdx.x >> 6;
    int lane = threadIdx.x & 63;
    int wgid = blockIdx.x * 4 + wid;   // global wave id
    int nbase = wgid * 4;              // first of this wave's 4 nodes
    if (nbase >= N) return;
    int c0 = lane * 2;
    int head = lane >> 4;

    float we00 = We[c0], we01 = We[c0 + 1];
    float we10 = We[HID + c0], we11 = We[HID + c0 + 1];
    float we20 = We[2 * HID + c0], we21 = We[2 * HID + c0 + 1];
    float at0 = att[head * CH + (c0 & 31)];
    float at1 = att[head * CH + (c0 & 31) + 1];

    float2 xrv[4];
    int beg[4], d[4];
    int maxd = 0;
#pragma unroll
    for (int j = 0; j < 4; j++) {
        int node = nbase + j;
        node = (node < N) ? node : (N - 1);
        xrv[j] = *(const float2*)&xr[(size_t)node * HID + c0];
        int b = rowstart[node], e = rowstart[node + 1];
        beg[j] = b;
        d[j] = (nbase + j < N) ? (e - b) : 0;
        maxd = max(maxd, d[j]);
    }
    maxd = __builtin_amdgcn_readfirstlane(maxd);

    float l[4] = {0.f, 0.f, 0.f, 0.f};
    float A0[4] = {0.f, 0.f, 0.f, 0.f};
    float A1[4] = {0.f, 0.f, 0.f, 0.f};

    for (int t = 0; t < maxd; t++) {
        int idx[4], s[4];
#pragma unroll
        for (int j = 0; j < 4; j++) {
            int tt = (t < d[j]) ? t : (d[j] - 1);
            tt = (tt > 0) ? tt : 0;
            idx[j] = (d[j] > 0) ? (beg[j] + tt) : 0;  // clamped; gated below
            s[j] = srcs[idx[j]];
        }
        float2 xv[4];
#pragma unroll
        for (int j = 0; j < 4; j++)
            xv[j] = *(const float2*)&xl[(size_t)s[j] * HID + c0];  // 4 indep gathers
        float4 ev[4];
#pragma unroll
        for (int j = 0; j < 4; j++) ev[j] = ea4[idx[j]];
#pragma unroll
        for (int j = 0; j < 4; j++) {
            float m0 = xv[j].x + xrv[j].x + fmaf(ev[j].x, we00, fmaf(ev[j].y, we10, ev[j].z * we20));
            float m1 = xv[j].y + xrv[j].y + fmaf(ev[j].x, we01, fmaf(ev[j].y, we11, ev[j].z * we21));
            m0 = (m0 > 0.f) ? m0 : SLOPE * m0;
            m1 = (m1 > 0.f) ? m1 : SLOPE * m1;
            float part = fmaf(m0, at0, m1 * at1);
            part += __shfl_xor(part, 1);
            part += __shfl_xor(part, 2);
            part += __shfl_xor(part, 4);
            part += __shfl_xor(part, 8);
            // softmax shift dropped: logits O(10), fp32-safe; clamped edges get p=0
            float p = (t < d[j]) ? __expf(part) : 0.f;
            l[j] += p;
            A0[j] = fmaf(p, xv[j].x, A0[j]);
            A1[j] = fmaf(p, xv[j].y, A1[j]);
        }
    }

    float ssum = 0.f, ssq = 0.f;
#pragma unroll
    for (int j = 0; j < 4; j++) {
        int node = nbase + j;
        if (node < N) {
            float inv = 1.f / (l[j] + 1e-16f);
            float o0 = A0[j] * inv, o1 = A1[j] * inv;
            *(float2*)&outp[(size_t)node * HID + c0] = make_float2(o0, o1);
            ssum += o0 + o1;
            ssq += fmaf(o0, o0, o1 * o1);
        }
    }
#pragma unroll
    for (int o = 32; o >= 1; o >>= 1) { ssum += __shfl_xor(ssum, o); ssq += __shfl_xor(ssq, o); }
    if (lane == 0) {
        int slot = (wgid & (RSLOTS - 1)) * 2;
        atomicAdd(&red[slot], ssum);
        atomicAdd(&red[slot + 1], ssq);
    }
}

// ---------------------------------------------------------------- LN finish + apply
__global__ __launch_bounds__(256) void k_finish(const float* __restrict__ red,
                                                float* __restrict__ scal, float M) {
    __shared__ float ls[8];
    int tid = threadIdx.x;
    float s = 0.f, q = 0.f;
    for (int i = tid; i < RSLOTS; i += 256) { s += red[2 * i]; q += red[2 * i + 1]; }
#pragma unroll
    for (int o = 32; o >= 1; o >>= 1) { s += __shfl_xor(s, o); q += __shfl_xor(q, o); }
    if ((tid & 63) == 0) { ls[(tid >> 6) * 2] = s; ls[(tid >> 6) * 2 + 1] = q; }
    __syncthreads();
    if (tid == 0) {
        float S = ls[0] + ls[2] + ls[4] + ls[6];
        float Q = ls[1] + ls[3] + ls[5] + ls[7];
        float mean = S / M;
        float var = Q / M - mean * mean;
        scal[0] = mean;
        scal[1] = rsqrtf(var + EPSLN);
    }
}

__global__ __launch_bounds__(256) void k_ln_gelu(const float4* __restrict__ in4,
                                                 const float* __restrict__ w,
                                                 const float* __restrict__ b,
                                                 const float* __restrict__ scal,
                                                 float4* __restrict__ out4, int n4) {
    int i = blockIdx.x * blockDim.x + threadIdx.x;
    if (i >= n4) return;
    float mean = scal[0], inv = scal[1];
    float4 v = in4[i];
    int col = (i * 4) & 127;
    float4 wv = *(const float4*)&w[col];
    float4 bv = *(const float4*)&b[col];
    float r[4] = {v.x, v.y, v.z, v.w};
    float wr[4] = {wv.x, wv.y, wv.z, wv.w};
    float br[4] = {bv.x, bv.y, bv.z, bv.w};
#pragma unroll
    for (int j = 0; j < 4; j++) {
        float t = fmaf((r[j] - mean) * inv, wr[j], br[j]);
        r[j] = 0.5f * t * (1.f + erff(t * 0.70710678118654752f));
    }
    out4[i] = make_float4(r[0], r[1], r[2], r[3]);
}

// ---------------------------------------------------------------- launch
extern "C" void kernel_launch(void* const* d_in, const int* in_sizes, int n_in,
                              void* d_out, int out_size, void* d_ws, size_t ws_size,
                              hipStream_t stream) {
    const float* x = (const float*)d_in[0];
    const int* ei = (const int*)d_in[1];
    const float* eattr = (const float*)d_in[2];
    const float* Wl = (const float*)d_in[3];
    const float* Wr = (const float*)d_in[4];
    const float* We = (const float*)d_in[5];
    const float* att = (const float*)d_in[6];
    const float* lnw = (const float*)d_in[7];
    const float* lnb = (const float*)d_in[8];
    const float* Wout = (const float*)d_in[9];
    const float* bout = (const float*)d_in[10];
    float* out = (float*)d_out;

    int N = in_sizes[0] / HID;
    int E = in_sizes[1] / 2;
    const int* src = ei;
    const int* dst = ei + E;

    char* w = (char*)d_ws;
    float* h_buf = (float*)w;   w += (size_t)N * HID * 4;
    float* tmp = (float*)w;     w += (size_t)N * HID * 4;
    float* xl = (float*)w;      w += (size_t)N * HID * 4;
    float* xr = (float*)w;      w += (size_t)N * HID * 4;
    float4* ea4 = (float4*)w;   w += (size_t)E * 16;
    float* red = (float*)w;     w += (size_t)RSLOTS * 2 * 4;
    float* scal = (float*)w;    w += 16;
    int* deg = (int*)w;         w += (size_t)N * 4;
    int* cursor = (int*)w;      w += (size_t)N * 4;
    int* rowstart = (int*)w;    w += (size_t)(N + 1) * 4;
    int* srcs = (int*)w;        w += (size_t)E * 4;

    // CSR build (graph identical across layers -> build once per call)
    hipMemsetAsync(deg, 0, (size_t)N * 4, stream);
    k_count<<<(E + 255) / 256, 256, 0, stream>>>(dst, deg, E);
    k_scan<<<1, 1024, 0, stream>>>(deg, rowstart, cursor, N);
    k_fill<<<(E + 255) / 256, 256, 0, stream>>>(src, dst, eattr, cursor, srcs, ea4, E);

    const float* hin = x;
    for (int l = 0; l < NLAYER; l++) {
        k_gemm128<<<dim3(640, 2), 256, 0, stream>>>(
            hin, Wl + (size_t)l * HID * HID, Wr + (size_t)l * HID * HID, xl, xr, nullptr, N);
        hipMemsetAsync(red, 0, (size_t)RSLOTS * 2 * 4, stream);
        k_aggregate<<<(N + 15) / 16, 256, 0, stream>>>(
            xl, xr, srcs, ea4, rowstart,
            We + (size_t)l * EDIM * HID, att + (size_t)l * NHEAD * CH, tmp, red, N);
        k_finish<<<1, 256, 0, stream>>>(red, scal, (float)N * (float)HID);
        k_ln_gelu<<<((N * HID / 4) + 255) / 256, 256, 0, stream>>>(
            (const float4*)tmp, lnw + (size_t)l * HID, lnb + (size_t)l * HID, scal,
            (float4*)h_buf, N * HID / 4);
        hin = h_buf;
    }
    k_gemm128<<<dim3(640, 1), 256, 0, stream>>>(hin, Wout, Wout, out, out, bout, N);
}